// Round 1
// baseline (383.072 us; speedup 1.0000x reference)
//
#include <hip/hip_runtime.h>
#include <hip/hip_fp16.h>

#define HW 4096
#define NC 192
#define NB 8
#define DQK 32   // padded qk depth (24 real + 8 zero)
#define QT 64    // q rows per block
#define MT 64    // m (key) tile

typedef _Float16 f16x8 __attribute__((ext_vector_type(8)));
typedef float f32x4 __attribute__((ext_vector_type(4)));

static __device__ __forceinline__ unsigned short f2h_bits(float f) {
  _Float16 h = (_Float16)f;
  union { _Float16 h; unsigned short u; } cv; cv.h = h; return cv.u;
}

// ---------------- projection: q = prelu(w1 x), k = prelu(w2 x), v = prelu(wa x)
// out layouts: Qn[b][pos][32] f16 (pad zero), Kn[b][pos][32] f16, Vt[b][c][pos] f16
__global__ __launch_bounds__(256) void proj_kernel(
    const float* __restrict__ x,
    const float* __restrict__ w1, const float* __restrict__ b1, const float* __restrict__ a1,
    const float* __restrict__ w2, const float* __restrict__ b2, const float* __restrict__ a2,
    const float* __restrict__ wa, const float* __restrict__ ba, const float* __restrict__ aa,
    unsigned short* __restrict__ Qn, unsigned short* __restrict__ Kn,
    unsigned short* __restrict__ Vt)
{
  const int b  = blockIdx.z;
  const int ot = blockIdx.y;          // out-channel tile of 16 (0..14) over concat[q24,k24,v192]
  const int p0 = blockIdx.x * 64;
  const int tid = threadIdx.x;

  __shared__ float xs[192][64];
  __shared__ float wsh[16][192];

  const float* xb = x + (size_t)b * NC * HW + p0;
  for (int i = tid; i < 192 * 64; i += 256) {
    int c = i >> 6, p = i & 63;
    xs[c][p] = xb[(size_t)c * HW + p];
  }
  for (int i = tid; i < 16 * 192; i += 256) {
    int oo = i / 192, c = i - oo * 192;
    int och = ot * 16 + oo;
    float wv;
    if (och < 24)      wv = w1[och * 192 + c];
    else if (och < 48) wv = w2[(och - 24) * 192 + c];
    else               wv = wa[(och - 48) * 192 + c];
    wsh[oo][c] = wv;
  }
  __syncthreads();

  const int p  = tid & 63;   // position lane (wave-contiguous)
  const int og = tid >> 6;   // wave id -> 4 out-channels, wave-uniform
  float a0 = 0.f, a1c = 0.f, a2c = 0.f, a3 = 0.f;
  #pragma unroll 4
  for (int c = 0; c < 192; ++c) {
    float xv = xs[c][p];
    a0  = fmaf(wsh[og * 4 + 0][c], xv, a0);
    a1c = fmaf(wsh[og * 4 + 1][c], xv, a1c);
    a2c = fmaf(wsh[og * 4 + 2][c], xv, a2c);
    a3  = fmaf(wsh[og * 4 + 3][c], xv, a3);
  }
  float accs[4] = {a0, a1c, a2c, a3};
  const int pos = p0 + p;
  #pragma unroll
  for (int i = 0; i < 4; ++i) {
    int och = ot * 16 + og * 4 + i;
    float bias, slope;
    if (och < 24)      { bias = b1[och];      slope = a1[0]; }
    else if (och < 48) { bias = b2[och - 24]; slope = a2[0]; }
    else               { bias = ba[och - 48]; slope = aa[0]; }
    float v = accs[i] + bias;
    v = (v >= 0.f) ? v : slope * v;
    unsigned short hb = f2h_bits(v);
    if (och < 24)      Qn[((size_t)b * HW + pos) * DQK + och] = hb;
    else if (och < 48) Kn[((size_t)b * HW + pos) * DQK + (och - 24)] = hb;
    else               Vt[((size_t)b * NC + (och - 48)) * HW + pos] = hb;
  }
}

// ---------------- flash attention: out[b][c][n] = sum_m softmax_m(Q[n].K[m]) V[c][m]
__global__ __launch_bounds__(256) void flash_kernel(
    const unsigned short* __restrict__ Qn, const unsigned short* __restrict__ Kn,
    const unsigned short* __restrict__ Vt, float* __restrict__ out)
{
  const int b    = blockIdx.y;
  const int q0   = blockIdx.x * QT;
  const int tid  = threadIdx.x;
  const int wv   = tid >> 6;    // wave 0..3
  const int lane = tid & 63;
  const int lq   = lane & 15;   // row/col-in-tile lane index
  const int lk   = lane >> 4;   // quarter

  __shared__ unsigned short Plds[QT][MT + 8];  // +8 halves: 144B stride, 16B aligned
  __shared__ float scaleL[QT];

  // Q A-fragment for this wave's 16 rows: A[i][k] = Q[q0+16w+i][k]
  f16x8 qfrag = *reinterpret_cast<const f16x8*>(
      Qn + ((size_t)b * HW + q0 + 16 * wv + lq) * DQK + 8 * lk);

  float m_run[4], l_run[4];
  f32x4 Oacc[4][3];
  #pragma unroll
  for (int r = 0; r < 4; ++r) { m_run[r] = -1e30f; l_run[r] = 0.f; }
  #pragma unroll
  for (int tr = 0; tr < 4; ++tr)
    #pragma unroll
    for (int tc = 0; tc < 3; ++tc)
      Oacc[tr][tc] = (f32x4){0.f, 0.f, 0.f, 0.f};

  for (int m0 = 0; m0 < HW; m0 += MT) {
    // ---- S = Q K^T for this wave's 16 rows x 64 cols
    f32x4 s[4];
    #pragma unroll
    for (int t = 0; t < 4; ++t) {
      f16x8 kfrag = *reinterpret_cast<const f16x8*>(
          Kn + ((size_t)b * HW + m0 + 16 * t + lq) * DQK + 8 * lk);
      s[t] = __builtin_amdgcn_mfma_f32_16x16x32_f16(qfrag, kfrag,
              (f32x4){0.f, 0.f, 0.f, 0.f}, 0, 0, 0);
    }
    // ---- online softmax (rows 4*lk+r of this wave's tile)
    #pragma unroll
    for (int r = 0; r < 4; ++r) {
      float mx = fmaxf(fmaxf(s[0][r], s[1][r]), fmaxf(s[2][r], s[3][r]));
      mx = fmaxf(mx, __shfl_xor(mx, 1));
      mx = fmaxf(mx, __shfl_xor(mx, 2));
      mx = fmaxf(mx, __shfl_xor(mx, 4));
      mx = fmaxf(mx, __shfl_xor(mx, 8));
      float mnew  = fmaxf(m_run[r], mx);
      float alpha = __expf(m_run[r] - mnew);
      float psum = 0.f;
      #pragma unroll
      for (int t = 0; t < 4; ++t) {
        float pv = __expf(s[t][r] - mnew);
        s[t][r] = pv;
        psum += pv;
      }
      psum += __shfl_xor(psum, 1);
      psum += __shfl_xor(psum, 2);
      psum += __shfl_xor(psum, 4);
      psum += __shfl_xor(psum, 8);
      l_run[r] = l_run[r] * alpha + psum;
      m_run[r] = mnew;
      int row = 16 * wv + 4 * lk + r;
      if (lq == 0) scaleL[row] = alpha;
      #pragma unroll
      for (int t = 0; t < 4; ++t)
        Plds[row][16 * t + lq] = f2h_bits(s[t][r]);
    }
    __syncthreads();
    // ---- rescale O, then O += P V^T (wave owns 48 v-channels, all 64 rows)
    #pragma unroll
    for (int tr = 0; tr < 4; ++tr) {
      float al[4];
      #pragma unroll
      for (int r = 0; r < 4; ++r) al[r] = scaleL[16 * tr + 4 * lk + r];
      #pragma unroll
      for (int tc = 0; tc < 3; ++tc)
        #pragma unroll
        for (int r = 0; r < 4; ++r) Oacc[tr][tc][r] *= al[r];
    }
    #pragma unroll
    for (int kk = 0; kk < 2; ++kk) {
      f16x8 pa[4];
      #pragma unroll
      for (int tr = 0; tr < 4; ++tr)
        pa[tr] = *reinterpret_cast<const f16x8*>(&Plds[16 * tr + lq][kk * 32 + 8 * lk]);
      #pragma unroll
      for (int tc = 0; tc < 3; ++tc) {
        f16x8 vb = *reinterpret_cast<const f16x8*>(
            Vt + ((size_t)b * NC + 48 * wv + 16 * tc + lq) * HW + m0 + kk * 32 + 8 * lk);
        #pragma unroll
        for (int tr = 0; tr < 4; ++tr)
          Oacc[tr][tc] = __builtin_amdgcn_mfma_f32_16x16x32_f16(pa[tr], vb, Oacc[tr][tc], 0, 0, 0);
      }
    }
    __syncthreads();
  }

  // ---- share row sums, normalize, write out[b][c][n]
  #pragma unroll
  for (int r = 0; r < 4; ++r)
    if (lq == 0) scaleL[16 * wv + 4 * lk + r] = l_run[r];
  __syncthreads();
  #pragma unroll
  for (int tr = 0; tr < 4; ++tr) {
    float inv[4];
    #pragma unroll
    for (int r = 0; r < 4; ++r) inv[r] = 1.f / scaleL[16 * tr + 4 * lk + r];
    #pragma unroll
    for (int tc = 0; tc < 3; ++tc)
      #pragma unroll
      for (int r = 0; r < 4; ++r)
        out[((size_t)b * NC + 48 * wv + 16 * tc + lq) * HW + q0 + 16 * tr + 4 * lk + r]
            = Oacc[tr][tc][r] * inv[r];
  }
}

extern "C" void kernel_launch(void* const* d_in, const int* in_sizes, int n_in,
                              void* d_out, int out_size, void* d_ws, size_t ws_size,
                              hipStream_t stream) {
  const float* x  = (const float*)d_in[0];
  const float* w1 = (const float*)d_in[1];
  const float* b1 = (const float*)d_in[2];
  const float* a1 = (const float*)d_in[3];
  const float* w2 = (const float*)d_in[4];
  const float* b2 = (const float*)d_in[5];
  const float* a2 = (const float*)d_in[6];
  const float* wa = (const float*)d_in[7];
  const float* ba = (const float*)d_in[8];
  const float* aa = (const float*)d_in[9];
  float* out = (float*)d_out;

  unsigned short* Qn = (unsigned short*)d_ws;                 // 8*4096*32 f16 = 2 MB
  unsigned short* Kn = Qn + (size_t)NB * HW * DQK;            // 2 MB
  unsigned short* Vt = Kn + (size_t)NB * HW * DQK;            // 8*192*4096 f16 = 12 MB

  // zero Q+K (covers the d=24..31 padding; Q pad zero makes K pad irrelevant)
  hipMemsetAsync(Qn, 0, (size_t)NB * HW * DQK * 2 * sizeof(unsigned short), stream);

  dim3 pgrid(HW / 64, 15, NB);
  proj_kernel<<<pgrid, 256, 0, stream>>>(x, w1, b1, a1, w2, b2, a2, wa, ba, aa, Qn, Kn, Vt);

  dim3 fgrid(HW / QT, NB);
  flash_kernel<<<fgrid, 256, 0, stream>>>(Qn, Kn, Vt, out);
}